// Round 11
// baseline (189.130 us; speedup 1.0000x reference)
//
#include <hip/hip_runtime.h>

#define NQv 20000
#define NSv 8192
#define Cv  112
#define CLSv 20
#define INFF 3.4e38f
#define JINF 0x7fffffff

#define GC 16
#define NCELL 4096
#define CELLH 8.0f
#define INVH 0.125f

#define POOLB 32
#define PT 256
#define PNW (POOLB * PT / 64)       // 128 pool waves -> 64 rows/wave

#define SBLK (NQv / 4)              // 5000 search blocks, wave-per-query
#define MB (NQv / 32)               // 625 mlp blocks
#define VP 36
// ws floats: [0,3616) pool partials; u16 start[4098] @ 3616; pts4 float4[8192] @ 5668
#define WS_START 3616
#define WS_PTS4  5668

// ---- prep: pool partials (blocks 0..31) + cell-sorted point table (block 32)
__global__ __launch_bounds__(PT) void k_prep(const float* __restrict__ cs,
                                             const float* __restrict__ fs7,
                                             const float* __restrict__ wat,
                                             float* __restrict__ ws) {
    int b = blockIdx.x, tid = threadIdx.x;

    if (b == POOLB) {               // grid build: histogram -> prefix -> scatter pts4
        __shared__ int cnt[NCELL];
        __shared__ int ssum[PT];
        unsigned short* startg = (unsigned short*)(ws + WS_START);
        float4* pts4 = (float4*)(ws + WS_PTS4);
        for (int i = tid; i < NCELL; i += PT) cnt[i] = 0;
        __syncthreads();
        for (int k = 0; k < NSv / PT; ++k) {
            int p = k * PT + tid;
            float x = cs[3 * p], y = cs[3 * p + 1], z = cs[3 * p + 2];
            int cx = (int)(x * INVH), cy = (int)(y * INVH), cz = (int)(z * INVH);
            cx = cx > 15 ? 15 : cx; cy = cy > 15 ? 15 : cy; cz = cz > 15 ? 15 : cz;
            atomicAdd(&cnt[(cz * GC + cy) * GC + cx], 1);
        }
        __syncthreads();
        int base = tid * 16, local = 0, c[16];
        #pragma unroll
        for (int i = 0; i < 16; ++i) { c[i] = cnt[base + i]; local += c[i]; }
        ssum[tid] = local;
        __syncthreads();
        for (int off = 1; off < PT; off <<= 1) {   // Hillis-Steele inclusive
            int v = (tid >= off) ? ssum[tid - off] : 0;
            __syncthreads();
            ssum[tid] += v;
            __syncthreads();
        }
        int run = ssum[tid] - local;
        #pragma unroll
        for (int i = 0; i < 16; ++i) {
            startg[base + i] = (unsigned short)run;
            cnt[base + i] = run;                   // cursor
            run += c[i];
        }
        if (tid == 0) startg[NCELL] = (unsigned short)NSv;
        __syncthreads();
        for (int k = 0; k < NSv / PT; ++k) {
            int p = k * PT + tid;
            float x = cs[3 * p], y = cs[3 * p + 1], z = cs[3 * p + 2];
            int cx = (int)(x * INVH), cy = (int)(y * INVH), cz = (int)(z * INVH);
            cx = cx > 15 ? 15 : cx; cy = cy > 15 ? 15 : cy; cz = cz > 15 ? 15 : cz;
            int slot = atomicAdd(&cnt[(cz * GC + cy) * GC + cx], 1);
            pts4[slot] = make_float4(-2.f * x, -2.f * y, -2.f * z, (float)p);
        }
        return;
    }

    // pool partials: ws[b*113 + c] = sum p_i*feat[i][c]; [...112] = sum p_i
    __shared__ float red[PT / 64][Cv + 1];
    int gtid = b * PT + tid;
    int wid = gtid >> 6, lw = tid >> 6, lane = gtid & 63, l2 = lane * 2;
    float2 wa = make_float2(0.f, 0.f);
    if (lane < 56) wa = *(const float2*)(wat + l2);
    float gx = 0.f, gy = 0.f, z = 0.f;
    for (int g = 0; g < 8; ++g) {               // 8 independent shuffle chains
        float2 f[8]; float part[8];
        #pragma unroll
        for (int u = 0; u < 8; ++u) {
            int i = wid + (g * 8 + u) * PNW;
            f[u] = (lane < 56) ? *(const float2*)(fs7 + i * Cv + l2) : make_float2(0.f, 0.f);
            part[u] = f[u].x * wa.x + f[u].y * wa.y;
        }
        #pragma unroll
        for (int off = 32; off; off >>= 1)
            #pragma unroll
            for (int u = 0; u < 8; ++u) part[u] += __shfl_xor(part[u], off, 64);
        #pragma unroll
        for (int u = 0; u < 8; ++u) {
            float p = __expf(part[u]);          // |logit| small, f32-safe
            gx = fmaf(p, f[u].x, gx); gy = fmaf(p, f[u].y, gy); z += p;
        }
    }
    if (lane < 56) { red[lw][l2] = gx; red[lw][l2 + 1] = gy; }
    if (lane == 0) red[lw][Cv] = z;
    __syncthreads();
    if (tid < Cv + 1)
        ws[b * (Cv + 1) + tid] = red[0][tid] + red[1][tid] + red[2][tid] + red[3][tid];
}

// point-stream lex-(e, idx) top-3 insert; canonical FMA chain for e
__device__ __forceinline__ void scan_run(const float4* __restrict__ pts4,
                                         int a, int b, float qx, float qy, float qz,
                                         float& E0, float& E1, float& E2,
                                         int& J0, int& J1, int& J2) {
    for (int k = a; k < b; ++k) {
        float4 P = pts4[k];
        float x = -0.5f * P.x, y = -0.5f * P.y, z = -0.5f * P.z;   // exact recover
        float s2 = fmaf(x, x, fmaf(y, y, z * z));
        float e = fmaf(qx, P.x, fmaf(qy, P.y, fmaf(qz, P.z, s2)));
        int j = (int)P.w;
        bool lt2 = (e < E2) || (e == E2 && j < J2);
        if (lt2) {
            bool lt1 = (e < E1) || (e == E1 && j < J1);
            bool lt0 = (e < E0) || (e == E0 && j < J0);
            E2 = lt1 ? E1 : e;              J2 = lt1 ? J1 : j;
            E1 = lt0 ? E0 : (lt1 ? e : E1); J1 = lt0 ? J0 : (lt1 ? j : J1);
            if (lt0) { E0 = e; J0 = j; }
        }
    }
}

// ---- search: ONE WAVE PER QUERY (20000 waves). Box cells on distinct lanes;
// ring expansion flat across lanes; exact lex pop-merge. Stash into d_out row.
__global__ __launch_bounds__(256) void k_search(const float* __restrict__ cq,
                                                const float* __restrict__ ws,
                                                float* __restrict__ out) {
    const unsigned short* __restrict__ startg = (const unsigned short*)(ws + WS_START);
    const float4* __restrict__ pts4 = (const float4*)(ws + WS_PTS4);
    int tid = threadIdx.x, lane = tid & 63, widx = tid >> 6;
    int q = blockIdx.x * 4 + widx;
    float qx = cq[3 * q], qy = cq[3 * q + 1], qz = cq[3 * q + 2];
    float q2 = fmaf(qx, qx, fmaf(qy, qy, qz * qz));
    int cx = (int)(qx * INVH), cy = (int)(qy * INVH), cz = (int)(qz * INVH);
    cx = cx > 15 ? 15 : cx; cy = cy > 15 ? 15 : cy; cz = cz > 15 ? 15 : cz;
    float E0 = INFF, E1 = INFF, E2 = INFF;
    int   J0 = JINF, J1 = JINF, J2 = JINF;

    // 3x3x3 box: one cell per lane (lane < 27)
    if (lane < 27) {
        int dz = lane / 9 - 1, dy = (lane / 3) % 3 - 1, dx = lane % 3 - 1;
        int xc = cx + dx, yc = cy + dy, zc = cz + dz;
        if ((unsigned)xc < 16u && (unsigned)yc < 16u && (unsigned)zc < 16u) {
            int cc = (zc * GC + yc) * GC + xc;
            scan_run(pts4, startg[cc], startg[cc + 1], qx, qy, qz, E0, E1, E2, J0, J1, J2);
        }
    }

    for (int s = 2; s <= 15; ++s) {
        // merged 3rd-best VALUE across 64 lanes (sorted-triple butterfly)
        float t0 = E0, t1 = E1, t2 = E2;
        #pragma unroll
        for (int off = 1; off < 64; off <<= 1) {
            float b0 = __shfl_xor(t0, off, 64);
            float b1 = __shfl_xor(t1, off, 64);
            float b2 = __shfl_xor(t2, off, 64);
            float xx = fmaxf(t0, b0), yy = fminf(t1, b1);
            float zz = fmaxf(t1, b1), uu = fminf(t2, b2);
            t0 = fminf(t0, b0);
            t1 = fminf(xx, yy);
            t2 = fminf(fminf(fmaxf(xx, yy), zz), uu);
        }
        // termination: searched half-width r = s-1 (wave-uniform)
        int r = s - 1;
        int xl = cx - r > 0 ? cx - r : 0, xh = cx + r < 15 ? cx + r : 15;
        int yl = cy - r > 0 ? cy - r : 0, yh = cy + r < 15 ? cy + r : 15;
        int zl = cz - r > 0 ? cz - r : 0, zh = cz + r < 15 ? cz + r : 15;
        float fx = INFF, fy = INFF, fz = INFF;
        if (xl > 0)  fx = qx - xl * CELLH;
        if (xh < 15) fx = fminf(fx, (xh + 1) * CELLH - qx);
        if (yl > 0)  fy = qy - yl * CELLH;
        if (yh < 15) fy = fminf(fy, (yh + 1) * CELLH - qy);
        if (zl > 0)  fz = qz - zl * CELLH;
        if (zh < 15) fz = fminf(fz, (zh + 1) * CELLH - qz);
        float dmin = fminf(fx, fminf(fy, fz));
        if (dmin * dmin > t2 + q2 + 0.5f) break;

        // Chebyshev ring s: flat enumeration of the (2s+1)^3 box across lanes,
        // interior (Chebyshev < s) and out-of-domain cells skipped
        int side = 2 * s + 1, s2n = side * side, tot = s2n * side;
        for (int idx = lane; idx < tot; idx += 64) {
            int dz = idx / s2n - s;
            int rem = idx - (dz + s) * s2n;
            int dy = rem / side - s;
            int dx = rem - (dy + s) * side - s;
            int ax = dx < 0 ? -dx : dx, ay = dy < 0 ? -dy : dy, az = dz < 0 ? -dz : dz;
            if (ax != s && ay != s && az != s) continue;
            int xc = cx + dx, yc = cy + dy, zc = cz + dz;
            if ((unsigned)xc > 15u || (unsigned)yc > 15u || (unsigned)zc > 15u) continue;
            int cc = (zc * GC + yc) * GC + xc;
            scan_run(pts4, startg[cc], startg[cc + 1], qx, qy, qz, E0, E1, E2, J0, J1, J2);
        }
    }

    // exact lex-(e,idx) pop-merge over 64 lanes (cells disjoint -> no duplicates)
    float h0 = E0, h1 = E1, h2 = E2; int g0 = J0, g1 = J1, g2 = J2;
    float EF[3]; int JF[3];
    #pragma unroll
    for (int t = 0; t < 3; ++t) {
        float mv = h0; int mj = g0;
        #pragma unroll
        for (int off = 1; off < 64; off <<= 1) {
            float ov = __shfl_xor(mv, off, 64);
            int   oj = __shfl_xor(mj, off, 64);
            if (ov < mv || (ov == mv && oj < mj)) { mv = ov; mj = oj; }
        }
        EF[t] = mv; JF[t] = mj;
        bool win = (h0 == mv) && (g0 == mj);
        h0 = win ? h1 : h0; g0 = win ? g1 : g0;
        h1 = win ? h2 : h1; g1 = win ? g2 : g1;
        h2 = win ? INFF : h2; g2 = win ? JINF : g2;
    }
    if (lane == 0) {
        int A0 = (JF[0] < 0 || JF[0] >= NSv) ? 0 : JF[0];
        int A1 = (JF[1] < 0 || JF[1] >= NSv) ? 0 : JF[1];
        int A2 = (JF[2] < 0 || JF[2] >= NSv) ? 0 : JF[2];
        ((int*)out)[q * CLSv]     = A0 | (A1 << 16);
        ((int*)out)[q * CLSv + 1] = A2;
    }
}

// ---- mlp: 512 threads / 8 waves, split-K pair GEMM. Unpack stash, recompute
// weights (bit-identical e), V^T build (vectorized), GEMMs, classifier.
__global__ __launch_bounds__(512, 4) void k_mlp(
        const float* __restrict__ cq, const float* __restrict__ cs,
        const float* __restrict__ x7, const float* __restrict__ fs,
        const float* __restrict__ W1, const float* __restrict__ gma,
        const float* __restrict__ bta, const float* __restrict__ W2,
        const float* __restrict__ Wc, const float* __restrict__ bc,
        const float* __restrict__ ws, float* __restrict__ out) {
    __shared__ float big[224 * VP];          // V^T -> h2^T
    __shared__ float tT[Cv * VP];            // h1 post-BN-ReLU
    __shared__ float gate[Cv];
    __shared__ int   qi[32][3];
    __shared__ float qw[32][3];

    int tid = threadIdx.x;
    int q0 = blockIdx.x * 32;

    if (tid < Cv) {                          // gate = sigmoid(pooled mean)
        float st = 0.f, zt = 0.f;
        for (int b = 0; b < POOLB; ++b) {
            st += ws[b * (Cv + 1) + tid];
            zt += ws[b * (Cv + 1) + Cv];
        }
        gate[tid] = 1.0f / (1.0f + __expf(-(st / zt)));
    }
    int ut = tid - 128;                      // unpack on a different wave pair
    if (ut >= 0 && ut < 32) {
        int q = q0 + ut;
        int A = ((const int*)out)[q * CLSv];
        int B = ((const int*)out)[q * CLSv + 1];
        int J0 = A & 0xFFFF, J1 = (A >> 16) & 0xFFFF, J2 = B;
        J0 = (J0 < 0 || J0 >= NSv) ? 0 : J0;
        J1 = (J1 < 0 || J1 >= NSv) ? 0 : J1;
        J2 = (J2 < 0 || J2 >= NSv) ? 0 : J2;
        float qx = cq[3 * q], qy = cq[3 * q + 1], qz = cq[3 * q + 2];
        float e[3]; int JJ[3] = {J0, J1, J2};
        #pragma unroll
        for (int r = 0; r < 3; ++r) {
            float x = cs[3 * JJ[r]], y = cs[3 * JJ[r] + 1], z = cs[3 * JJ[r] + 2];
            float s2 = fmaf(x, x, fmaf(y, y, z * z));
            e[r] = fmaf(qx, -2.f * x, fmaf(qy, -2.f * y, fmaf(qz, -2.f * z, s2)));
        }
        float w1v = __expf(e[0] - e[1]);
        float w2v = __expf(e[0] - e[2]);
        float iw  = 1.0f / (1.0f + w1v + w2v);
        qw[ut][0] = iw; qw[ut][1] = w1v * iw; qw[ut][2] = w2v * iw;
        qi[ut][0] = J0; qi[ut][1] = J1; qi[ut][2] = J2;
    }
    __syncthreads();

    // build V^T[224][VP]: rows 0..111 = gated x7 (float4 loads), 112..223 = matched
    {
        int vq = tid >> 4, e16 = tid & 15;   // 16 threads per query
        int gq = q0 + vq;
        const float4* __restrict__ x4 = (const float4*)(x7 + gq * Cv);
        #pragma unroll
        for (int r = 0; r < 2; ++r) {
            int f4 = e16 + r * 16;
            if (f4 < 28) {
                float4 v = x4[f4];
                int k = f4 * 4;
                big[(k    ) * VP + vq] = v.x * gate[k];
                big[(k + 1) * VP + vq] = v.y * gate[k + 1];
                big[(k + 2) * VP + vq] = v.z * gate[k + 2];
                big[(k + 3) * VP + vq] = v.w * gate[k + 3];
            }
        }
        int i0 = qi[vq][0], i1 = qi[vq][1], i2 = qi[vq][2];
        float w0 = qw[vq][0], w1v = qw[vq][1], w2v = qw[vq][2];
        #pragma unroll
        for (int r = 0; r < 7; ++r) {
            int k = e16 + (r << 4);
            float m = w0 * fs[i0 * Cv + k] + w1v * fs[i1 * Cv + k] + w2v * fs[i2 * Cv + k];
            big[(Cv + k) * VP + vq] = m;
        }
    }
    __syncthreads();

    // split-K pair GEMM: lanes (2t, 2t+1) share tile t (4q x 4c), opposite K halves
    int tt = tid >> 1, kh = tid & 1;
    int cb = (tt % 28) * 4, qb = (tt / 28) * 4;      // tt < 224

    if (tid < 448) {                         // h1 = V @ W1 -> BN affine -> ReLU
        float acc[4][4] = {};
        int k0 = kh * 112;
        #pragma unroll 4
        for (int i = 0; i < 112; ++i) {
            int k = k0 + i;
            float4 vv = *(const float4*)&big[k * VP + qb];
            float4 ww = *(const float4*)&W1[k * Cv + cb];
            #pragma unroll
            for (int i2_ = 0; i2_ < 4; ++i2_) {
                float v = (&vv.x)[i2_];
                acc[i2_][0] = fmaf(v, ww.x, acc[i2_][0]);
                acc[i2_][1] = fmaf(v, ww.y, acc[i2_][1]);
                acc[i2_][2] = fmaf(v, ww.z, acc[i2_][2]);
                acc[i2_][3] = fmaf(v, ww.w, acc[i2_][3]);
            }
        }
        #pragma unroll
        for (int j = 0; j < 4; ++j)
            #pragma unroll
            for (int i = 0; i < 4; ++i)
                acc[i][j] += __shfl_xor(acc[i][j], 1, 64);
        if (kh == 0) {
            #pragma unroll
            for (int j = 0; j < 4; ++j) {
                float g = gma[cb + j], b = bta[cb + j];
                #pragma unroll
                for (int i = 0; i < 4; ++i) {
                    float hh = fmaf(acc[i][j], g, b);
                    tT[(cb + j) * VP + qb + i] = hh > 0.f ? hh : 0.f;
                }
            }
        }
    }
    __syncthreads();

    if (tid < 448) {                         // h2 = t @ W2
        float acc[4][4] = {};
        int k0 = kh * 56;
        #pragma unroll 4
        for (int i = 0; i < 56; ++i) {
            int k = k0 + i;
            float4 vv = *(const float4*)&tT[k * VP + qb];
            float4 ww = *(const float4*)&W2[k * Cv + cb];
            #pragma unroll
            for (int i2_ = 0; i2_ < 4; ++i2_) {
                float v = (&vv.x)[i2_];
                acc[i2_][0] = fmaf(v, ww.x, acc[i2_][0]);
                acc[i2_][1] = fmaf(v, ww.y, acc[i2_][1]);
                acc[i2_][2] = fmaf(v, ww.z, acc[i2_][2]);
                acc[i2_][3] = fmaf(v, ww.w, acc[i2_][3]);
            }
        }
        #pragma unroll
        for (int j = 0; j < 4; ++j)
            #pragma unroll
            for (int i = 0; i < 4; ++i)
                acc[i][j] += __shfl_xor(acc[i][j], 1, 64);
        if (kh == 0) {
            #pragma unroll
            for (int j = 0; j < 4; ++j)
                #pragma unroll
                for (int i = 0; i < 4; ++i)
                    big[(cb + j) * VP + qb + i] = acc[i][j];
        }
    }
    __syncthreads();

    // out = h2 @ Wc + bc : 640 items (32q x 20c) over 512 threads
    for (int o = tid; o < 32 * CLSv; o += 512) {
        int qq = o & 31, c = o >> 5;
        float a = bc[c];
        #pragma unroll 4
        for (int k = 0; k < Cv; ++k)
            a = fmaf(big[k * VP + qq], Wc[k * CLSv + c], a);
        out[(q0 + qq) * CLSv + c] = a;
    }
}

extern "C" void kernel_launch(void* const* d_in, const int* in_sizes, int n_in,
                              void* d_out, int out_size, void* d_ws, size_t ws_size,
                              hipStream_t stream) {
    const float* cq  = (const float*)d_in[0];
    const float* cs  = (const float*)d_in[1];
    const float* x7  = (const float*)d_in[2];
    const float* fs7 = (const float*)d_in[3];
    const float* fs  = (const float*)d_in[4];
    const float* wat = (const float*)d_in[5];
    const float* W1  = (const float*)d_in[6];
    const float* gma = (const float*)d_in[7];
    const float* bta = (const float*)d_in[8];
    const float* W2  = (const float*)d_in[9];
    const float* Wc  = (const float*)d_in[10];
    const float* bc  = (const float*)d_in[11];
    float* ws  = (float*)d_ws;
    float* out = (float*)d_out;

    k_prep<<<POOLB + 1, PT, 0, stream>>>(cs, fs7, wat, ws);
    k_search<<<SBLK, 256, 0, stream>>>(cq, ws, out);
    k_mlp<<<MB, 512, 0, stream>>>(cq, cs, x7, fs, W1, gma, bta, W2, Wc, bc, ws, out);
}

// Round 12
// 158.701 us; speedup vs baseline: 1.1917x; 1.1917x over previous
//
#include <hip/hip_runtime.h>

#define NQv 20000
#define NSv 8192
#define Cv  112
#define CLSv 20
#define INFF 3.4e38f
#define JINF 0x7fffffff

#define GC 16
#define NCELL 4096
#define CELLH 8.0f
#define INVH 0.125f

#define POOLB 32
#define PT 256
#define PNW (POOLB * PT / 64)

#define SBLK (NQv / 4)              // 5000 search blocks, wave-per-query
#define MB (NQv / 32)               // 625 mlp blocks
// ws floats: [0,3616) pool; u16 start[4098] @3616; pts4 @5668; bf16 weight tables after
#define WS_START 3616
#define WS_PTS4  5668
#define WS_W1TH  38440              // u16 [112][224] bf16-hi of W1^T
#define WS_W1TL  50984              // u16 [112][224] bf16-lo
#define WS_W2TH  63528              // u16 [112][128] (K zero-padded)
#define WS_W2TL  70696
#define WS_WCT   77864              // f32 [20][112] Wc^T

typedef __attribute__((ext_vector_type(8))) short bf16x8;   // 8 bf16 = 4 VGPRs
typedef __attribute__((ext_vector_type(4))) float f32x4;
typedef unsigned short us;

__device__ __forceinline__ float bf2f(us u) {
    union { unsigned int i; float f; } v; v.i = ((unsigned int)u) << 16; return v.f;
}
__device__ __forceinline__ us f2bf(float f) {
    union { float f; unsigned int i; } v; v.f = f;
    unsigned int r = v.i + 0x7fffu + ((v.i >> 16) & 1u);
    return (us)(r >> 16);
}
__device__ __forceinline__ void split(float v, us& h, us& l) {
    h = f2bf(v); l = f2bf(v - bf2f(h));
}

// ---- prep: pool (0..31) + grid build (32) + weight tables (33,34)
__global__ __launch_bounds__(PT) void k_prep(const float* __restrict__ cs,
                                             const float* __restrict__ fs7,
                                             const float* __restrict__ wat,
                                             const float* __restrict__ W1,
                                             const float* __restrict__ W2,
                                             const float* __restrict__ Wc,
                                             float* __restrict__ ws) {
    int b = blockIdx.x, tid = threadIdx.x;

    if (b == POOLB + 1) {           // W1^T bf16 hi/lo tables
        us* w1h = (us*)(ws + WS_W1TH);
        us* w1l = (us*)(ws + WS_W1TL);
        for (int idx = tid; idx < Cv * 224; idx += PT) {
            int c = idx / 224, k = idx - c * 224;
            us h, l; split(W1[k * Cv + c], h, l);
            w1h[c * 224 + k] = h; w1l[c * 224 + k] = l;
        }
        return;
    }
    if (b == POOLB + 2) {           // W2^T (K padded to 128) + Wc^T
        us* w2h = (us*)(ws + WS_W2TH);
        us* w2l = (us*)(ws + WS_W2TL);
        for (int idx = tid; idx < Cv * 128; idx += PT) {
            int c = idx >> 7, k = idx & 127;
            float v = (k < Cv) ? W2[k * Cv + c] : 0.f;
            us h, l; split(v, h, l);
            w2h[c * 128 + k] = h; w2l[c * 128 + k] = l;
        }
        float* wct = ws + WS_WCT;
        for (int idx = tid; idx < CLSv * Cv; idx += PT) {
            int cls = idx / Cv, k = idx - cls * Cv;
            wct[cls * Cv + k] = Wc[k * CLSv + cls];
        }
        return;
    }
    if (b == POOLB) {               // grid build: histogram -> prefix -> scatter pts4
        __shared__ int cnt[NCELL];
        __shared__ int ssum[PT];
        us* startg = (us*)(ws + WS_START);
        float4* pts4 = (float4*)(ws + WS_PTS4);
        for (int i = tid; i < NCELL; i += PT) cnt[i] = 0;
        __syncthreads();
        for (int k = 0; k < NSv / PT; ++k) {
            int p = k * PT + tid;
            float x = cs[3 * p], y = cs[3 * p + 1], z = cs[3 * p + 2];
            int cx = (int)(x * INVH), cy = (int)(y * INVH), cz = (int)(z * INVH);
            cx = cx > 15 ? 15 : cx; cy = cy > 15 ? 15 : cy; cz = cz > 15 ? 15 : cz;
            atomicAdd(&cnt[(cz * GC + cy) * GC + cx], 1);
        }
        __syncthreads();
        int base = tid * 16, local = 0, c[16];
        #pragma unroll
        for (int i = 0; i < 16; ++i) { c[i] = cnt[base + i]; local += c[i]; }
        ssum[tid] = local;
        __syncthreads();
        for (int off = 1; off < PT; off <<= 1) {
            int v = (tid >= off) ? ssum[tid - off] : 0;
            __syncthreads();
            ssum[tid] += v;
            __syncthreads();
        }
        int run = ssum[tid] - local;
        #pragma unroll
        for (int i = 0; i < 16; ++i) {
            startg[base + i] = (us)run;
            cnt[base + i] = run;
            run += c[i];
        }
        if (tid == 0) startg[NCELL] = (us)NSv;
        __syncthreads();
        for (int k = 0; k < NSv / PT; ++k) {
            int p = k * PT + tid;
            float x = cs[3 * p], y = cs[3 * p + 1], z = cs[3 * p + 2];
            int cx = (int)(x * INVH), cy = (int)(y * INVH), cz = (int)(z * INVH);
            cx = cx > 15 ? 15 : cx; cy = cy > 15 ? 15 : cy; cz = cz > 15 ? 15 : cz;
            int slot = atomicAdd(&cnt[(cz * GC + cy) * GC + cx], 1);
            pts4[slot] = make_float4(-2.f * x, -2.f * y, -2.f * z, (float)p);
        }
        return;
    }

    // pool partials
    __shared__ float red[PT / 64][Cv + 1];
    int gtid = b * PT + tid;
    int wid = gtid >> 6, lw = tid >> 6, lane = gtid & 63, l2 = lane * 2;
    float2 wa = make_float2(0.f, 0.f);
    if (lane < 56) wa = *(const float2*)(wat + l2);
    float gx = 0.f, gy = 0.f, z = 0.f;
    for (int g = 0; g < 8; ++g) {
        float2 f[8]; float part[8];
        #pragma unroll
        for (int u = 0; u < 8; ++u) {
            int i = wid + (g * 8 + u) * PNW;
            f[u] = (lane < 56) ? *(const float2*)(fs7 + i * Cv + l2) : make_float2(0.f, 0.f);
            part[u] = f[u].x * wa.x + f[u].y * wa.y;
        }
        #pragma unroll
        for (int off = 32; off; off >>= 1)
            #pragma unroll
            for (int u = 0; u < 8; ++u) part[u] += __shfl_xor(part[u], off, 64);
        #pragma unroll
        for (int u = 0; u < 8; ++u) {
            float p = __expf(part[u]);
            gx = fmaf(p, f[u].x, gx); gy = fmaf(p, f[u].y, gy); z += p;
        }
    }
    if (lane < 56) { red[lw][l2] = gx; red[lw][l2 + 1] = gy; }
    if (lane == 0) red[lw][Cv] = z;
    __syncthreads();
    if (tid < Cv + 1)
        ws[b * (Cv + 1) + tid] = red[0][tid] + red[1][tid] + red[2][tid] + red[3][tid];
}

// point-stream lex-(e, idx) top-3 insert; canonical FMA chain for e
__device__ __forceinline__ void scan_run(const float4* __restrict__ pts4,
                                         int a, int b, float qx, float qy, float qz,
                                         float& E0, float& E1, float& E2,
                                         int& J0, int& J1, int& J2) {
    for (int k = a; k < b; ++k) {
        float4 P = pts4[k];
        float x = -0.5f * P.x, y = -0.5f * P.y, z = -0.5f * P.z;
        float s2 = fmaf(x, x, fmaf(y, y, z * z));
        float e = fmaf(qx, P.x, fmaf(qy, P.y, fmaf(qz, P.z, s2)));
        int j = (int)P.w;
        bool lt2 = (e < E2) || (e == E2 && j < J2);
        if (lt2) {
            bool lt1 = (e < E1) || (e == E1 && j < J1);
            bool lt0 = (e < E0) || (e == E0 && j < J0);
            E2 = lt1 ? E1 : e;              J2 = lt1 ? J1 : j;
            E1 = lt0 ? E0 : (lt1 ? e : E1); J1 = lt0 ? J0 : (lt1 ? j : J1);
            if (lt0) { E0 = e; J0 = j; }
        }
    }
}

// ---- search: one wave per query (unchanged from round 10)
__global__ __launch_bounds__(256) void k_search(const float* __restrict__ cq,
                                                const float* __restrict__ ws,
                                                float* __restrict__ out) {
    const us* __restrict__ startg = (const us*)(ws + WS_START);
    const float4* __restrict__ pts4 = (const float4*)(ws + WS_PTS4);
    int tid = threadIdx.x, lane = tid & 63, widx = tid >> 6;
    int q = blockIdx.x * 4 + widx;
    float qx = cq[3 * q], qy = cq[3 * q + 1], qz = cq[3 * q + 2];
    float q2 = fmaf(qx, qx, fmaf(qy, qy, qz * qz));
    int cx = (int)(qx * INVH), cy = (int)(qy * INVH), cz = (int)(qz * INVH);
    cx = cx > 15 ? 15 : cx; cy = cy > 15 ? 15 : cy; cz = cz > 15 ? 15 : cz;
    float E0 = INFF, E1 = INFF, E2 = INFF;
    int   J0 = JINF, J1 = JINF, J2 = JINF;

    if (lane < 27) {
        int dz = lane / 9 - 1, dy = (lane / 3) % 3 - 1, dx = lane % 3 - 1;
        int xc = cx + dx, yc = cy + dy, zc = cz + dz;
        if ((unsigned)xc < 16u && (unsigned)yc < 16u && (unsigned)zc < 16u) {
            int cc = (zc * GC + yc) * GC + xc;
            scan_run(pts4, startg[cc], startg[cc + 1], qx, qy, qz, E0, E1, E2, J0, J1, J2);
        }
    }
    for (int s = 2; s <= 15; ++s) {
        float t0 = E0, t1 = E1, t2 = E2;
        #pragma unroll
        for (int off = 1; off < 64; off <<= 1) {
            float b0 = __shfl_xor(t0, off, 64);
            float b1 = __shfl_xor(t1, off, 64);
            float b2 = __shfl_xor(t2, off, 64);
            float xx = fmaxf(t0, b0), yy = fminf(t1, b1);
            float zz = fmaxf(t1, b1), uu = fminf(t2, b2);
            t0 = fminf(t0, b0);
            t1 = fminf(xx, yy);
            t2 = fminf(fminf(fmaxf(xx, yy), zz), uu);
        }
        int r = s - 1;
        int xl = cx - r > 0 ? cx - r : 0, xh = cx + r < 15 ? cx + r : 15;
        int yl = cy - r > 0 ? cy - r : 0, yh = cy + r < 15 ? cy + r : 15;
        int zl = cz - r > 0 ? cz - r : 0, zh = cz + r < 15 ? cz + r : 15;
        float fx = INFF, fy = INFF, fz = INFF;
        if (xl > 0)  fx = qx - xl * CELLH;
        if (xh < 15) fx = fminf(fx, (xh + 1) * CELLH - qx);
        if (yl > 0)  fy = qy - yl * CELLH;
        if (yh < 15) fy = fminf(fy, (yh + 1) * CELLH - qy);
        if (zl > 0)  fz = qz - zl * CELLH;
        if (zh < 15) fz = fminf(fz, (zh + 1) * CELLH - qz);
        float dmin = fminf(fx, fminf(fy, fz));
        if (dmin * dmin > t2 + q2 + 0.5f) break;

        int side = 2 * s + 1, s2n = side * side, tot = s2n * side;
        for (int idx = lane; idx < tot; idx += 64) {
            int dz = idx / s2n - s;
            int rem = idx - (dz + s) * s2n;
            int dy = rem / side - s;
            int dx = rem - (dy + s) * side - s;
            int ax = dx < 0 ? -dx : dx, ay = dy < 0 ? -dy : dy, az = dz < 0 ? -dz : dz;
            if (ax != s && ay != s && az != s) continue;
            int xc = cx + dx, yc = cy + dy, zc = cz + dz;
            if ((unsigned)xc > 15u || (unsigned)yc > 15u || (unsigned)zc > 15u) continue;
            int cc = (zc * GC + yc) * GC + xc;
            scan_run(pts4, startg[cc], startg[cc + 1], qx, qy, qz, E0, E1, E2, J0, J1, J2);
        }
    }
    float h0 = E0, h1 = E1, h2 = E2; int g0 = J0, g1 = J1, g2 = J2;
    float EF[3]; int JF[3];
    #pragma unroll
    for (int t = 0; t < 3; ++t) {
        float mv = h0; int mj = g0;
        #pragma unroll
        for (int off = 1; off < 64; off <<= 1) {
            float ov = __shfl_xor(mv, off, 64);
            int   oj = __shfl_xor(mj, off, 64);
            if (ov < mv || (ov == mv && oj < mj)) { mv = ov; mj = oj; }
        }
        EF[t] = mv; JF[t] = mj;
        bool win = (h0 == mv) && (g0 == mj);
        h0 = win ? h1 : h0; g0 = win ? g1 : g0;
        h1 = win ? h2 : h1; g1 = win ? g2 : g1;
        h2 = win ? INFF : h2; g2 = win ? JINF : g2;
    }
    if (lane == 0) {
        int A0 = (JF[0] < 0 || JF[0] >= NSv) ? 0 : JF[0];
        int A1 = (JF[1] < 0 || JF[1] >= NSv) ? 0 : JF[1];
        int A2 = (JF[2] < 0 || JF[2] >= NSv) ? 0 : JF[2];
        ((int*)out)[q * CLSv]     = A0 | (A1 << 16);
        ((int*)out)[q * CLSv + 1] = A2;
    }
}

// ---- mlp: MFMA split-bf16 GEMMs. 448 threads (7 waves), 32 queries/block.
// Wave w owns output channels [16w,16w+16); M-tiles q[0:16), q[16:32).
__global__ __launch_bounds__(448) void k_mlp(
        const float* __restrict__ cq, const float* __restrict__ cs,
        const float* __restrict__ x7, const float* __restrict__ fs,
        const float* __restrict__ gma, const float* __restrict__ bta,
        const float* __restrict__ bc, const float* __restrict__ ws,
        float* __restrict__ out) {
    __shared__ __align__(16) us vbh[32 * 232];   // V bf16-hi, stride 232 (bank-safe)
    __shared__ __align__(16) us vbl[32 * 232];
    __shared__ __align__(16) us hbh[32 * 136];   // h1 bf16-hi, K padded to 128
    __shared__ __align__(16) us hbl[32 * 136];
    __shared__ __align__(16) float h2f[32 * 116];
    __shared__ float gate[Cv];
    __shared__ int   qi[32][3];
    __shared__ float qw[32][3];

    int tid = threadIdx.x;
    int q0 = blockIdx.x * 32;

    if (tid < Cv) {                              // gate = sigmoid(pooled mean)
        float st = 0.f, zt = 0.f;
        for (int b = 0; b < POOLB; ++b) {
            st += ws[b * (Cv + 1) + tid];
            zt += ws[b * (Cv + 1) + Cv];
        }
        gate[tid] = 1.0f / (1.0f + __expf(-(st / zt)));
    }
    int ut = tid - 128;                          // unpack stash + recompute weights
    if (ut >= 0 && ut < 32) {
        int q = q0 + ut;
        int A = ((const int*)out)[q * CLSv];
        int B = ((const int*)out)[q * CLSv + 1];
        int J0 = A & 0xFFFF, J1 = (A >> 16) & 0xFFFF, J2 = B;
        J0 = (J0 < 0 || J0 >= NSv) ? 0 : J0;
        J1 = (J1 < 0 || J1 >= NSv) ? 0 : J1;
        J2 = (J2 < 0 || J2 >= NSv) ? 0 : J2;
        float qx = cq[3 * q], qy = cq[3 * q + 1], qz = cq[3 * q + 2];
        float e[3]; int JJ[3] = {J0, J1, J2};
        #pragma unroll
        for (int r = 0; r < 3; ++r) {
            float x = cs[3 * JJ[r]], y = cs[3 * JJ[r] + 1], z = cs[3 * JJ[r] + 2];
            float s2 = fmaf(x, x, fmaf(y, y, z * z));
            e[r] = fmaf(qx, -2.f * x, fmaf(qy, -2.f * y, fmaf(qz, -2.f * z, s2)));
        }
        float w1v = __expf(e[0] - e[1]);
        float w2v = __expf(e[0] - e[2]);
        float iw  = 1.0f / (1.0f + w1v + w2v);
        qw[ut][0] = iw; qw[ut][1] = w1v * iw; qw[ut][2] = w2v * iw;
        qi[ut][0] = J0; qi[ut][1] = J1; qi[ut][2] = J2;
    }
    for (int i = tid; i < 32 * 16; i += 448) {   // zero h1 K-pad (k=112..127)
        int q = i >> 4, kk = Cv + (i & 15);
        hbh[q * 136 + kk] = 0; hbl[q * 136 + kk] = 0;
    }
    __syncthreads();

    // build V[32][224] as bf16 hi/lo: 14 threads/query x 16 k each
    {
        int vq = tid / 14, e = tid - vq * 14;
        int gq = q0 + vq;
        int k0 = e * 16;
        float vals[16];
        if (e < 7) {
            const float4* xr = (const float4*)(x7 + gq * Cv + k0);
            #pragma unroll
            for (int i = 0; i < 4; ++i) {
                float4 v = xr[i];
                vals[i * 4]     = v.x * gate[k0 + i * 4];
                vals[i * 4 + 1] = v.y * gate[k0 + i * 4 + 1];
                vals[i * 4 + 2] = v.z * gate[k0 + i * 4 + 2];
                vals[i * 4 + 3] = v.w * gate[k0 + i * 4 + 3];
            }
        } else {
            int kk = k0 - Cv;
            float w0 = qw[vq][0], w1v = qw[vq][1], w2v = qw[vq][2];
            const float4* r0 = (const float4*)(fs + qi[vq][0] * Cv + kk);
            const float4* r1 = (const float4*)(fs + qi[vq][1] * Cv + kk);
            const float4* r2 = (const float4*)(fs + qi[vq][2] * Cv + kk);
            #pragma unroll
            for (int i = 0; i < 4; ++i) {
                float4 a = r0[i], b = r1[i], c = r2[i];
                vals[i * 4]     = w0 * a.x + w1v * b.x + w2v * c.x;
                vals[i * 4 + 1] = w0 * a.y + w1v * b.y + w2v * c.y;
                vals[i * 4 + 2] = w0 * a.z + w1v * b.z + w2v * c.z;
                vals[i * 4 + 3] = w0 * a.w + w1v * b.w + w2v * c.w;
            }
        }
        #pragma unroll
        for (int i = 0; i < 16; ++i) {
            us h, l; split(vals[i], h, l);
            vbh[vq * 232 + k0 + i] = h;
            vbl[vq * 232 + k0 + i] = l;
        }
    }
    __syncthreads();

    int w = tid >> 6, lane = tid & 63, quad = lane >> 4, l16 = lane & 15;
    int cc = w * 16 + l16;                       // this lane's output channel

    // GEMM1: h1 = V @ W1  (K=224, 7 ksteps, 3 MFMA terms each, 2 M-tiles)
    {
        f32x4 acc0 = {0.f, 0.f, 0.f, 0.f};
        f32x4 acc1 = {0.f, 0.f, 0.f, 0.f};
        const us* w1h = (const us*)(ws + WS_W1TH) + cc * 224;
        const us* w1l = (const us*)(ws + WS_W1TL) + cc * 224;
        #pragma unroll
        for (int ks = 0; ks < 7; ++ks) {
            int ko = ks * 32 + quad * 8;
            bf16x8 bh  = *(const bf16x8*)(w1h + ko);
            bf16x8 bl  = *(const bf16x8*)(w1l + ko);
            bf16x8 a0h = *(const bf16x8*)(vbh + l16 * 232 + ko);
            bf16x8 a0l = *(const bf16x8*)(vbl + l16 * 232 + ko);
            bf16x8 a1h = *(const bf16x8*)(vbh + (l16 + 16) * 232 + ko);
            bf16x8 a1l = *(const bf16x8*)(vbl + (l16 + 16) * 232 + ko);
            acc0 = __builtin_amdgcn_mfma_f32_16x16x32_bf16(a0h, bh, acc0, 0, 0, 0);
            acc0 = __builtin_amdgcn_mfma_f32_16x16x32_bf16(a0l, bh, acc0, 0, 0, 0);
            acc0 = __builtin_amdgcn_mfma_f32_16x16x32_bf16(a0h, bl, acc0, 0, 0, 0);
            acc1 = __builtin_amdgcn_mfma_f32_16x16x32_bf16(a1h, bh, acc1, 0, 0, 0);
            acc1 = __builtin_amdgcn_mfma_f32_16x16x32_bf16(a1l, bh, acc1, 0, 0, 0);
            acc1 = __builtin_amdgcn_mfma_f32_16x16x32_bf16(a1h, bl, acc1, 0, 0, 0);
        }
        float g = gma[cc], bb = bta[cc];
        #pragma unroll
        for (int r = 0; r < 4; ++r) {            // D row = quad*4+r, col = cc
            int q = quad * 4 + r;
            float h = fmaf(acc0[r], g, bb); h = h > 0.f ? h : 0.f;
            us hh, ll; split(h, hh, ll);
            hbh[q * 136 + cc] = hh; hbl[q * 136 + cc] = ll;
            float h2 = fmaf(acc1[r], g, bb); h2 = h2 > 0.f ? h2 : 0.f;
            split(h2, hh, ll);
            hbh[(q + 16) * 136 + cc] = hh; hbl[(q + 16) * 136 + cc] = ll;
        }
    }
    __syncthreads();

    // GEMM2: h2 = h1 @ W2  (K=128 padded, 4 ksteps)
    {
        f32x4 acc0 = {0.f, 0.f, 0.f, 0.f};
        f32x4 acc1 = {0.f, 0.f, 0.f, 0.f};
        const us* w2h = (const us*)(ws + WS_W2TH) + cc * 128;
        const us* w2l = (const us*)(ws + WS_W2TL) + cc * 128;
        #pragma unroll
        for (int ks = 0; ks < 4; ++ks) {
            int ko = ks * 32 + quad * 8;
            bf16x8 bh  = *(const bf16x8*)(w2h + ko);
            bf16x8 bl  = *(const bf16x8*)(w2l + ko);
            bf16x8 a0h = *(const bf16x8*)(hbh + l16 * 136 + ko);
            bf16x8 a0l = *(const bf16x8*)(hbl + l16 * 136 + ko);
            bf16x8 a1h = *(const bf16x8*)(hbh + (l16 + 16) * 136 + ko);
            bf16x8 a1l = *(const bf16x8*)(hbl + (l16 + 16) * 136 + ko);
            acc0 = __builtin_amdgcn_mfma_f32_16x16x32_bf16(a0h, bh, acc0, 0, 0, 0);
            acc0 = __builtin_amdgcn_mfma_f32_16x16x32_bf16(a0l, bh, acc0, 0, 0, 0);
            acc0 = __builtin_amdgcn_mfma_f32_16x16x32_bf16(a0h, bl, acc0, 0, 0, 0);
            acc1 = __builtin_amdgcn_mfma_f32_16x16x32_bf16(a1h, bh, acc1, 0, 0, 0);
            acc1 = __builtin_amdgcn_mfma_f32_16x16x32_bf16(a1l, bh, acc1, 0, 0, 0);
            acc1 = __builtin_amdgcn_mfma_f32_16x16x32_bf16(a1h, bl, acc1, 0, 0, 0);
        }
        #pragma unroll
        for (int r = 0; r < 4; ++r) {
            int q = quad * 4 + r;
            h2f[q * 116 + cc] = acc0[r];
            h2f[(q + 16) * 116 + cc] = acc1[r];
        }
    }
    __syncthreads();

    // classifier: out = h2 @ Wc + bc (f32 VALU, WcT rows contiguous)
    for (int it = tid; it < 32 * CLSv; it += 448) {
        int cls = it % CLSv, qq = it / CLSv;
        const float4* wr = (const float4*)(ws + WS_WCT + cls * Cv);
        const float4* hr = (const float4*)(h2f + qq * 116);
        float a = bc[cls];
        #pragma unroll 7
        for (int i = 0; i < 28; ++i) {
            float4 h = hr[i], v = wr[i];
            a = fmaf(h.x, v.x, fmaf(h.y, v.y, fmaf(h.z, v.z, fmaf(h.w, v.w, a))));
        }
        out[(q0 + qq) * CLSv + cls] = a;
    }
}

extern "C" void kernel_launch(void* const* d_in, const int* in_sizes, int n_in,
                              void* d_out, int out_size, void* d_ws, size_t ws_size,
                              hipStream_t stream) {
    const float* cq  = (const float*)d_in[0];
    const float* cs  = (const float*)d_in[1];
    const float* x7  = (const float*)d_in[2];
    const float* fs7 = (const float*)d_in[3];
    const float* fs  = (const float*)d_in[4];
    const float* wat = (const float*)d_in[5];
    const float* W1  = (const float*)d_in[6];
    const float* gma = (const float*)d_in[7];
    const float* bta = (const float*)d_in[8];
    const float* W2  = (const float*)d_in[9];
    const float* Wc  = (const float*)d_in[10];
    const float* bc  = (const float*)d_in[11];
    float* ws  = (float*)d_ws;
    float* out = (float*)d_out;

    k_prep<<<POOLB + 3, PT, 0, stream>>>(cs, fs7, wat, W1, W2, Wc, ws);
    k_search<<<SBLK, 256, 0, stream>>>(cq, ws, out);
    k_mlp<<<MB, 448, 0, stream>>>(cq, cs, x7, fs, gma, bta, bc, ws, out);
}